// Round 1
// baseline (570.248 us; speedup 1.0000x reference)
//
#include <hip/hip_runtime.h>
#include <hip/hip_bf16.h>

#define K_DIM 4096
#define N_DIM 12288
#define B_DIM 64
#define G_DIM 64          // K / 64 groups
#define R_DIM 32
#define NT_DIM 768        // N / 16 n-tiles

typedef int v4i __attribute__((ext_vector_type(4)));

__device__ __forceinline__ int pack4(const v4i a) {
    return (a.x & 255) | ((a.y & 255) << 8) | ((a.z & 255) << 16) | (a.w << 24);
}

// ---------------------------------------------------------------------------
// Kernel 1: fused quantize + lora-down partial (R6 version — unchanged).
// ---------------------------------------------------------------------------
__global__ __launch_bounds__(256) void quant_lora_kernel(
    const float* __restrict__ x, const float* __restrict__ smooth,
    const float* __restrict__ ld, char* __restrict__ xq_p,
    float* __restrict__ ascale, float* __restrict__ t_part) {
    const int b = blockIdx.x >> 4;
    const int kc = blockIdx.x & 15;
    const int tid = threadIdx.x;
    const int k = kc * 256 + tid;

    __shared__ float sx[256];
    __shared__ float red[256];

    const float xd = x[b * K_DIM + k] / smooth[k];
    sx[tid] = xd;

    // --- quant (wave == group) ---
    const int lane = tid & 63;
    float a = fabsf(xd);
    #pragma unroll
    for (int off = 32; off; off >>= 1) a = fmaxf(a, __shfl_xor(a, off));
    const float as = fmaxf(a / 7.0f, 1e-8f);
    float q = rintf(xd / as);
    q = fminf(fmaxf(q, -8.0f), 7.0f);
    const int g = kc * 4 + (tid >> 6);
    const int bt = b >> 4, b15 = b & 15;
    const int quad = lane >> 4, kin = lane & 15;
    xq_p[((((size_t)bt * G_DIM + g) * 64) + quad * 16 + b15) * 16 + kin] = (char)(int)q;
    if (lane == 0) ascale[b * G_DIM + g] = as;
    __syncthreads();

    // --- lora-down partial over this 256-k chunk ---
    const int r = tid & 31, c = tid >> 5;     // c = 0..7
    const int kb = kc * 256 + c * 32;
    float acc = 0.f;
    #pragma unroll 8
    for (int kk = 0; kk < 32; ++kk)
        acc += sx[c * 32 + kk] * ld[(size_t)(kb + kk) * R_DIM + r];
    red[tid] = acc;
    __syncthreads();
    if (tid < 32) {
        float s = 0.f;
        #pragma unroll
        for (int c2 = 0; c2 < 8; ++c2) s += red[c2 * 32 + tid];
        t_part[kc * (B_DIM * R_DIM) + b * R_DIM + tid] = s;
    }
}

// ---------------------------------------------------------------------------
// Kernel 2: fused main — R7: 2-deep register prefetch (qaA/qaB), pack-first
// iteration order, never drain vmcnt to 0 in the loop (T4 principle).
//   even half: issue qaA<-chunk j+2 ; pack qaB(j+1)->buf1 ; compute(j,buf0) ; bar
//   odd  half: issue qaB<-chunk j+3 ; pack qaA(j+2)->buf0 ; compute(j+1,buf1); bar
// Compiler emits vmcnt(4) before each pack (just-issued loads stay in flight);
// issue->wait distance = one full chunk-iteration (pack+compute+barrier) vs
// R6's compute-only (~350cy). Chunk0/1 loads issue BEFORE the preamble stages
// so HBM is busy during the s_t 16-slice reduction.
// 2 LDS buffers still race-free: pack target != compute source within a phase;
// trailing barrier separates generations. LDS 38.4 KB -> 3 blocks/CU.
// __launch_bounds__(256,3) pins VGPR <=170 (R6 post-mortem: spills past that
// cost 112 MB scratch; 2 blocks/CU forces a second grid round = 1.5x time).
// ---------------------------------------------------------------------------
__global__ __launch_bounds__(256, 3) void main_fused_kernel(
    const int* __restrict__ qw, const float* __restrict__ wscales,
    const v4i* __restrict__ xq_p, const float* __restrict__ ascale,
    const float* __restrict__ t_part, const float* __restrict__ lora_up,
    const float* __restrict__ bias, float* __restrict__ out) {
    __shared__ float s_ws[G_DIM * 16];      // [g][j]   4 KB
    __shared__ float s_as[G_DIM * 68];      // [g][b]  17 KB (pad 68)
    __shared__ float s_t[B_DIM * R_DIM];    // [b][r]   8 KB
    __shared__ int   s_qp[2][1088];         // 2 x (16 rows x 272 B) packed

    const int nt = blockIdx.x;
    const int n0 = nt * 16;
    const int tid = threadIdx.x;

    // staging-role indices
    const int srow = tid >> 4;              // 0..15  (n-row within tile)
    const int scol = tid & 15;              // 0..15  (4-int32 col group)
    const int* gptr = qw + (size_t)(n0 + srow) * K_DIM + scol * 4;

    // issue chunk0 + chunk1 weight loads FIRST: HBM busy during preamble
    v4i qaA[4], qaB[4];
    #pragma unroll
    for (int i = 0; i < 4; ++i) qaA[i] = *(const v4i*)(gptr + i * 64);
    #pragma unroll
    for (int i = 0; i < 4; ++i) qaB[i] = *(const v4i*)(gptr + 256 + i * 64);

    // one-time LDS stages (overlap with in-flight weight loads)
    for (int i = tid; i < G_DIM * 16; i += 256)
        s_ws[i] = wscales[(i >> 4) * N_DIM + n0 + (i & 15)];
    for (int i = tid; i < B_DIM * G_DIM; i += 256) {
        const int b = i >> 6, g = i & 63;
        s_as[g * 68 + b] = ascale[i];
    }
    for (int i = tid; i < B_DIM * R_DIM; i += 256) {
        float s = 0.f;
        #pragma unroll
        for (int kc = 0; kc < 16; ++kc) s += t_part[kc * (B_DIM * R_DIM) + i];
        s_t[i] = s;
    }

    // pack chunk0 -> buf0 (compiler: vmcnt(4), qaB stays in flight)
    #pragma unroll
    for (int i = 0; i < 4; ++i)
        s_qp[0][srow * 68 + i * 16 + scol] = pack4(qaA[i]);
    __syncthreads();

    const int w = tid >> 6, lane = tid & 63;
    const int col = lane & 15, quad = lane >> 4;

    float facc[4] = {0.f, 0.f, 0.f, 0.f};
    const v4i zero = {0, 0, 0, 0};
    const v4i* xbase = xq_p + (size_t)w * G_DIM * 64 + lane;
    const char* rdbase0 = (const char*)&s_qp[0][0] + col * 272 + quad * 16;
    const char* rdbase1 = (const char*)&s_qp[1][0] + col * 272 + quad * 16;

#define ISSUE(QA, CHUNK)                                                     \
    {                                                                        \
        const int* p_ = gptr + (CHUNK) * 256;                                \
        _Pragma("unroll")                                                    \
        for (int i = 0; i < 4; ++i) QA[i] = *(const v4i*)(p_ + i * 64);      \
    }
#define PACK(QA, BUF)                                                        \
    {                                                                        \
        _Pragma("unroll")                                                    \
        for (int i = 0; i < 4; ++i)                                          \
            s_qp[BUF][srow * 68 + i * 16 + scol] = pack4(QA[i]);             \
    }
#define COMPUTE_CHUNK(JC, RDB)                                               \
    {                                                                        \
        _Pragma("unroll")                                                    \
        for (int gi = 0; gi < 4; ++gi) {                                     \
            const int g = (JC) * 4 + gi;                                     \
            const v4i bq = *(const v4i*)((RDB) + gi * 64);                   \
            const v4i xa = xbase[(size_t)g * 64];                            \
            const v4i d =                                                    \
                __builtin_amdgcn_mfma_i32_16x16x64_i8(xa, bq, zero, 0, 0, 0);\
            const float wsc = s_ws[g * 16 + col];                            \
            const float4 as4 =                                               \
                *(const float4*)&s_as[g * 68 + w * 16 + quad * 4];           \
            facc[0] = fmaf(as4.x * wsc, (float)d[0], facc[0]);               \
            facc[1] = fmaf(as4.y * wsc, (float)d[1], facc[1]);               \
            facc[2] = fmaf(as4.z * wsc, (float)d[2], facc[2]);               \
            facc[3] = fmaf(as4.w * wsc, (float)d[3], facc[3]);               \
        }                                                                    \
    }

    for (int j = 0; j < 16; j += 2) {
        // ---- even half: buf0 holds chunk j (ready); qaB holds chunk j+1 ----
        if (j + 2 < 16) ISSUE(qaA, j + 2);
        PACK(qaB, 1);                       // vmcnt(4): qaA loads keep flying
        COMPUTE_CHUNK(j, rdbase0);
        __syncthreads();
        // ---- odd half: buf1 holds chunk j+1; qaA holds chunk j+2 ----
        if (j + 3 < 16) ISSUE(qaB, j + 3);
        if (j + 2 < 16) PACK(qaA, 0);
        COMPUTE_CHUNK(j + 1, rdbase1);
        if (j + 2 < 16) __syncthreads();
    }

#undef ISSUE
#undef PACK
#undef COMPUTE_CHUNK

    // ---- epilogue: bias + rank-32 lora, direct store ----
    const int n = n0 + col;
    float4 lu[8];
    {
        const float4* lp = (const float4*)(lora_up + (size_t)n * R_DIM);
        #pragma unroll
        for (int i = 0; i < 8; ++i) lu[i] = lp[i];
    }
    const float bs = bias[n];
    #pragma unroll
    for (int r = 0; r < 4; ++r) {
        const int b = w * 16 + quad * 4 + r;
        float acc = facc[r] + bs;
        #pragma unroll
        for (int r2 = 0; r2 < 8; ++r2) {
            const float4 tv = *(const float4*)&s_t[b * R_DIM + r2 * 4];
            acc += tv.x * lu[r2].x + tv.y * lu[r2].y +
                   tv.z * lu[r2].z + tv.w * lu[r2].w;
        }
        out[(size_t)b * N_DIM + n] = acc;
    }
}

// ---------------------------------------------------------------------------
extern "C" void kernel_launch(void* const* d_in, const int* in_sizes, int n_in,
                              void* d_out, int out_size, void* d_ws, size_t ws_size,
                              hipStream_t stream) {
    const float* x         = (const float*)d_in[0];
    const int*   q_w       = (const int*)d_in[1];
    const float* wscales   = (const float*)d_in[2];
    const float* lora_down = (const float*)d_in[3];
    const float* lora_up   = (const float*)d_in[4];
    const float* smooth    = (const float*)d_in[5];
    const float* bias      = (const float*)d_in[6];
    float* out = (float*)d_out;

    char*  xq     = (char*)d_ws;                            // 256 KB packed
    float* ascale = (float*)((char*)d_ws + 262144);         // 16 KB
    float* t_part = (float*)((char*)d_ws + 262144 + 16384); // 128 KB (16 slices)

    quant_lora_kernel<<<B_DIM * 16, 256, 0, stream>>>(x, smooth, lora_down,
                                                      xq, ascale, t_part);
    main_fused_kernel<<<NT_DIM, 256, 0, stream>>>(q_w, wscales, (const v4i*)xq,
                                                  ascale, t_part, lora_up, bias, out);
}

// Round 3
// 320.073 us; speedup vs baseline: 1.7816x; 1.7816x over previous
//
#include <hip/hip_runtime.h>
#include <hip/hip_bf16.h>

#define K_DIM 4096
#define N_DIM 12288
#define B_DIM 64
#define G_DIM 64          // K / 64 groups
#define R_DIM 32
#define NT_DIM 768        // N / 16 n-tiles

typedef int v4i __attribute__((ext_vector_type(4)));

__device__ __forceinline__ int pack4(const v4i a) {
    return (a.x & 255) | ((a.y & 255) << 8) | ((a.z & 255) << 16) | (a.w << 24);
}

// ---------------------------------------------------------------------------
// Kernel 0 (R9 new): weight repack int32 -> int8, MFMA-lane-swizzled layout.
// Dest 16-B unit index t = ((nt*64 + g)*64 + lane); lane = quad*16 + col
// maps to source row n = nt*16 + col, bytes k = g*64 + quad*16.
// This is the SAME layout kernel1 uses for xq, so the main kernel's bq load
// becomes base + lane*16B: one fully-coalesced 1 KB/wave dwordx4 per group.
// Pure streaming: 201 MB read + 50 MB write, no LDS, no barriers -> ~40 us.
// ---------------------------------------------------------------------------
__global__ __launch_bounds__(256) void repack_kernel(
    const int* __restrict__ qw, char* __restrict__ pw) {
    const size_t t = (size_t)blockIdx.x * 256 + threadIdx.x;  // 16-B unit id
    const int lane = (int)(t & 63);
    const int g    = (int)((t >> 6) & 63);
    const int nt   = (int)(t >> 12);
    const int col = lane & 15, quad = lane >> 4;
    const int* src = qw + (size_t)(nt * 16 + col) * K_DIM + g * 64 + quad * 16;
    const v4i a0 = *(const v4i*)(src);
    const v4i a1 = *(const v4i*)(src + 4);
    const v4i a2 = *(const v4i*)(src + 8);
    const v4i a3 = *(const v4i*)(src + 12);
    v4i r;
    r.x = pack4(a0); r.y = pack4(a1); r.z = pack4(a2); r.w = pack4(a3);
    *(v4i*)(pw + t * 16) = r;
}

// ---------------------------------------------------------------------------
// Kernel 1: fused quantize + lora-down partial (R6 version — unchanged,
// proven in the 297.7 us baseline).
// ---------------------------------------------------------------------------
__global__ __launch_bounds__(256) void quant_lora_kernel(
    const float* __restrict__ x, const float* __restrict__ smooth,
    const float* __restrict__ ld, char* __restrict__ xq_p,
    float* __restrict__ ascale, float* __restrict__ t_part) {
    const int b = blockIdx.x >> 4;
    const int kc = blockIdx.x & 15;
    const int tid = threadIdx.x;
    const int k = kc * 256 + tid;

    __shared__ float sx[256];
    __shared__ float red[256];

    const float xd = x[b * K_DIM + k] / smooth[k];
    sx[tid] = xd;

    // --- quant (wave == group) ---
    const int lane = tid & 63;
    float a = fabsf(xd);
    #pragma unroll
    for (int off = 32; off; off >>= 1) a = fmaxf(a, __shfl_xor(a, off));
    const float as = fmaxf(a / 7.0f, 1e-8f);
    float q = rintf(xd / as);
    q = fminf(fmaxf(q, -8.0f), 7.0f);
    const int g = kc * 4 + (tid >> 6);
    const int bt = b >> 4, b15 = b & 15;
    const int quad = lane >> 4, kin = lane & 15;
    xq_p[((((size_t)bt * G_DIM + g) * 64) + quad * 16 + b15) * 16 + kin] = (char)(int)q;
    if (lane == 0) ascale[b * G_DIM + g] = as;
    __syncthreads();

    // --- lora-down partial over this 256-k chunk ---
    const int r = tid & 31, c = tid >> 5;     // c = 0..7
    const int kb = kc * 256 + c * 32;
    float acc = 0.f;
    #pragma unroll 8
    for (int kk = 0; kk < 32; ++kk)
        acc += sx[c * 32 + kk] * ld[(size_t)(kb + kk) * R_DIM + r];
    red[tid] = acc;
    __syncthreads();
    if (tid < 32) {
        float s = 0.f;
        #pragma unroll
        for (int c2 = 0; c2 < 8; ++c2) s += red[c2 * 32 + tid];
        t_part[kc * (B_DIM * R_DIM) + b * R_DIM + tid] = s;
    }
}

// ---------------------------------------------------------------------------
// Kernel 2: main — R9: BARRIER-FREE K-loop on pre-packed weights.
// R7/R8 post-mortem: the stage+pack+barrier pipeline was both schedule-
// fragile (R8 NaN at higher VGPR budget, root cause not found) and
// structurally capped (__syncthreads drains vmcnt(0) -> prefetch dies at
// every barrier; all 12 waves/CU lockstep on the same drain).
// R9 removes the structure: weights arrive already int8-packed in the
// MFMA-lane-swizzled layout, so the K-loop per group is just
//   bq = pw[(nt*64+g)*64 + lane]   (1 KB/wave coalesced, L3/L2-resident)
//   xa = xq [( w*64+g)*64 + lane]  (1 KB/wave coalesced, L2-resident)
//   mfma_i32_16x16x64_i8 + 4 scale-FMAs
// with ZERO __syncthreads after the preamble. No lockstep; latency hidden
// by TLP (LDS 29.4 KB -> 5 blocks/CU, ~20 waves/CU) + unroll-4 ILP.
// All 4 waves of a block read the same bq stream -> L1 reuse x4.
// ---------------------------------------------------------------------------
__global__ __launch_bounds__(256) void main_fused_kernel(
    const v4i* __restrict__ pw, const float* __restrict__ wscales,
    const v4i* __restrict__ xq_p, const float* __restrict__ ascale,
    const float* __restrict__ t_part, const float* __restrict__ lora_up,
    const float* __restrict__ bias, float* __restrict__ out) {
    __shared__ float s_ws[G_DIM * 16];      // [g][j]   4 KB
    __shared__ float s_as[G_DIM * 68];      // [g][b]  17 KB (pad 68)
    __shared__ float s_t[B_DIM * R_DIM];    // [b][r]   8 KB

    const int nt = blockIdx.x;
    const int n0 = nt * 16;
    const int tid = threadIdx.x;

    // one-time LDS stages
    for (int i = tid; i < G_DIM * 16; i += 256)
        s_ws[i] = wscales[(i >> 4) * N_DIM + n0 + (i & 15)];
    for (int i = tid; i < B_DIM * G_DIM; i += 256) {
        const int b = i >> 6, g = i & 63;
        s_as[g * 68 + b] = ascale[i];
    }
    for (int i = tid; i < B_DIM * R_DIM; i += 256) {
        float s = 0.f;
        #pragma unroll
        for (int kc = 0; kc < 16; ++kc) s += t_part[kc * (B_DIM * R_DIM) + i];
        s_t[i] = s;
    }
    __syncthreads();                        // the ONLY block barrier

    const int w = tid >> 6, lane = tid & 63;
    const int col = lane & 15, quad = lane >> 4;

    float facc[4] = {0.f, 0.f, 0.f, 0.f};
    const v4i zero = {0, 0, 0, 0};
    const v4i* xbase = xq_p + (size_t)w * G_DIM * 64 + lane;   // [w][g][lane]
    const v4i* bbase = pw + (size_t)nt * G_DIM * 64 + lane;    // [nt][g][lane]

    #pragma unroll 4
    for (int g = 0; g < G_DIM; ++g) {
        const v4i bq = bbase[g * 64];
        const v4i xa = xbase[g * 64];
        const v4i d = __builtin_amdgcn_mfma_i32_16x16x64_i8(xa, bq, zero, 0, 0, 0);
        const float wsc = s_ws[g * 16 + col];
        const float4 as4 = *(const float4*)&s_as[g * 68 + w * 16 + quad * 4];
        facc[0] = fmaf(as4.x * wsc, (float)d[0], facc[0]);
        facc[1] = fmaf(as4.y * wsc, (float)d[1], facc[1]);
        facc[2] = fmaf(as4.z * wsc, (float)d[2], facc[2]);
        facc[3] = fmaf(as4.w * wsc, (float)d[3], facc[3]);
    }

    // ---- epilogue: bias + rank-32 lora, direct store ----
    const int n = n0 + col;
    float4 lu[8];
    {
        const float4* lp = (const float4*)(lora_up + (size_t)n * R_DIM);
        #pragma unroll
        for (int i = 0; i < 8; ++i) lu[i] = lp[i];
    }
    const float bs = bias[n];
    #pragma unroll
    for (int r = 0; r < 4; ++r) {
        const int b = w * 16 + quad * 4 + r;
        float acc = facc[r] + bs;
        #pragma unroll
        for (int r2 = 0; r2 < 8; ++r2) {
            const float4 tv = *(const float4*)&s_t[b * R_DIM + r2 * 4];
            acc += tv.x * lu[r2].x + tv.y * lu[r2].y +
                   tv.z * lu[r2].z + tv.w * lu[r2].w;
        }
        out[(size_t)b * N_DIM + n] = acc;
    }
}

// ---------------------------------------------------------------------------
extern "C" void kernel_launch(void* const* d_in, const int* in_sizes, int n_in,
                              void* d_out, int out_size, void* d_ws, size_t ws_size,
                              hipStream_t stream) {
    const float* x         = (const float*)d_in[0];
    const int*   q_w       = (const int*)d_in[1];
    const float* wscales   = (const float*)d_in[2];
    const float* lora_down = (const float*)d_in[3];
    const float* lora_up   = (const float*)d_in[4];
    const float* smooth    = (const float*)d_in[5];
    const float* bias      = (const float*)d_in[6];
    float* out = (float*)d_out;

    char*  xq     = (char*)d_ws;                            // 256 KB packed acts
    float* ascale = (float*)((char*)d_ws + 262144);         // 16 KB
    float* t_part = (float*)((char*)d_ws + 262144 + 16384); // 128 KB (16 slices)
    char*  pw     = (char*)d_ws + 409600;                   // 48 MB packed weights

    // packed-weight units: N*K/16 = 3,145,728 -> 12288 blocks x 256 threads
    repack_kernel<<<(N_DIM / 16) * (K_DIM / 16) * (16 * 16 / 16) / 256, 256, 0,
                    stream>>>(q_w, pw);
    quant_lora_kernel<<<B_DIM * 16, 256, 0, stream>>>(x, smooth, lora_down,
                                                      xq, ascale, t_part);
    main_fused_kernel<<<NT_DIM, 256, 0, stream>>>((const v4i*)pw, wscales,
                                                  (const v4i*)xq, ascale,
                                                  t_part, lora_up, bias, out);
}